// Round 10
// baseline (647.368 us; speedup 1.0000x reference)
//
#include <hip/hip_runtime.h>
#include <math.h>

// ---- geometry constants (match reference) ----
#define NA   24
#define NU   128
#define NV   64
#define NW   128   // volume W (x)
#define NH   128   // volume H (y)
#define ND   64    // volume D (z)
#define NS   128   // samples per ray
#define F_STEP 1.5625f            // 2*HS/S = 200/128
#define F_DL  (200.0f / 127.0f)   // linspace(156,356,128) spacing
#define F_L0  156.0f
#define INV_DL (127.0f / 200.0f)

#define NRAYS (NA * NV * NU)      // 196608
#define VOX   (NW * NH * ND)      // 1048576
#define RT_PITCH 8448             // per-angle floats: 132 u-cols * 64 v (4 zero pad cols)

typedef float v2f __attribute__((ext_vector_type(2)));

// cos/sin(k*15 deg)
__device__ __constant__ float CSA[NA] = {
    1.0f,  0.96592582628906829f,  0.86602540378443865f,  0.70710678118654752f,
    0.5f,  0.25881904510252076f,  0.0f,                 -0.25881904510252076f,
   -0.5f, -0.70710678118654752f, -0.86602540378443865f, -0.96592582628906829f,
   -1.0f, -0.96592582628906829f, -0.86602540378443865f, -0.70710678118654752f,
   -0.5f, -0.25881904510252076f,  0.0f,                  0.25881904510252076f,
    0.5f,  0.70710678118654752f,  0.86602540378443865f,  0.96592582628906829f
};
__device__ __constant__ float SNA[NA] = {
    0.0f,  0.25881904510252076f,  0.5f,                  0.70710678118654752f,
    0.86602540378443865f,  0.96592582628906829f,  1.0f,  0.96592582628906829f,
    0.86602540378443865f,  0.70710678118654752f,  0.5f,  0.25881904510252076f,
    0.0f, -0.25881904510252076f, -0.5f,                 -0.70710678118654752f,
   -0.86602540378443865f, -0.96592582628906829f, -1.0f, -0.96592582628906829f,
   -0.86602540378443865f, -0.70710678118654752f, -0.5f, -0.25881904510252076f
};

// Per-ray geometry for FP.
__device__ __forceinline__ void ray_setup(int a, int v, int u,
                                          float& sx, float& sy,
                                          float& dx, float& dy, float& dz) {
    float ang = (float)((double)a * (15.0 * M_PI / 180.0));
    float c = cosf(ang), s = sinf(ang);
    float uu = (float)u - 63.5f;
    float vv = (float)v - 31.5f;
    float ux = 512.0f * c - uu * s;
    float uy = 512.0f * s + uu * c;
    float uz = vv;
    float invn = 1.0f / sqrtf(ux * ux + uy * uy + uz * uz);
    dx = ux * invn; dy = uy * invn; dz = uz * invn;
    sx = -256.0f * c; sy = -256.0f * s;
}

// ---------------- forward projection, segmented over ell ----------------
__global__ __launch_bounds__(256) void fp_seg_kernel(const float* __restrict__ vol,
                                                     float* __restrict__ part) {
    int r = blockIdx.x * blockDim.x + threadIdx.x;
    int seg = blockIdx.y;
    int u = r & (NU - 1);
    int v = (r >> 7) & (NV - 1);
    int a = r >> 13;

    float sx, sy, dx, dy, dz;
    ray_setup(a, v, u, sx, sy, dx, dy, dz);

    float rx = 1.0f / dx, ry = 1.0f / dy, rz = 1.0f / dz;
    float ex0 = (-64.55f - sx) * rx, ex1 = (64.55f - sx) * rx;
    float ey0 = (-64.55f - sy) * ry, ey1 = (64.55f - sy) * ry;
    float ez0 = (-32.55f) * rz,      ez1 = (32.55f) * rz;
    float llo = fmaxf(fmaxf(fminf(ex0, ex1), fminf(ey0, ey1)), fminf(ez0, ez1));
    float lhi = fminf(fminf(fmaxf(ex0, ex1), fmaxf(ey0, ey1)), fmaxf(ez0, ez1));
    int i_lo = max(seg * 64,      (int)ceilf((llo - F_L0) * INV_DL));
    int i_hi = min(seg * 64 + 63, (int)floorf((lhi - F_L0) * INV_DL));

    float acc = 0.0f;
    for (int i = i_lo; i <= i_hi; ++i) {
        float ell = F_L0 + F_DL * (float)i;
        float cx = sx + ell * dx + 63.5f;
        float cy = sy + ell * dy + 63.5f;
        float cz =      ell * dz + 31.5f;
        float fx = floorf(cx), fy = floorf(cy), fz = floorf(cz);
        int ix = (int)fx, iy = (int)fy, iz = (int)fz;
        float wx1 = cx - fx, wy1 = cy - fy, wz1 = cz - fz;
        float wx0 = 1.0f - wx1, wy0 = 1.0f - wy1, wz0 = 1.0f - wz1;
        bool bx0 = (unsigned)ix < NW,      bx1 = (unsigned)(ix + 1) < NW;
        bool by0 = (unsigned)iy < NH,      by1 = (unsigned)(iy + 1) < NH;
        bool bz0 = (unsigned)iz < ND,      bz1 = (unsigned)(iz + 1) < ND;
        long base = ((long)iz * NH + iy) * NW + ix;
        float v000 = (bz0 && by0 && bx0) ? vol[base]                 : 0.0f;
        float v001 = (bz0 && by0 && bx1) ? vol[base + 1]             : 0.0f;
        float v010 = (bz0 && by1 && bx0) ? vol[base + NW]            : 0.0f;
        float v011 = (bz0 && by1 && bx1) ? vol[base + NW + 1]        : 0.0f;
        float v100 = (bz1 && by0 && bx0) ? vol[base + NH * NW]       : 0.0f;
        float v101 = (bz1 && by0 && bx1) ? vol[base + NH * NW + 1]   : 0.0f;
        float v110 = (bz1 && by1 && bx0) ? vol[base + NH * NW + NW]  : 0.0f;
        float v111 = (bz1 && by1 && bx1) ? vol[base + NH * NW + NW + 1] : 0.0f;
        acc += wz0 * (wy0 * (wx0 * v000 + wx1 * v001) +
                      wy1 * (wx0 * v010 + wx1 * v011)) +
               wz1 * (wy0 * (wx0 * v100 + wx1 * v101) +
                      wy1 * (wx0 * v110 + wx1 * v111));
    }
    part[seg * NRAYS + r] = acc;
}

// ------- residual + cw + Ram-Lak; writes TRANSPOSED resT[a][u][v] with zeroed pad cols -------
__global__ __launch_bounds__(NU) void ramp_kernel(const float* __restrict__ part,
                                                  const float* __restrict__ p,
                                                  float* __restrict__ resT) {
    __shared__ float row[NU];
    int rowid = blockIdx.x;          // a*NV + v
    int u = threadIdx.x;
    int e = rowid * NU + u;
    int a = rowid >> 6;
    int v = rowid & (NV - 1);
    float sino = (part[e] + part[NRAYS + e]) * F_STEP;
    double du = (double)u - 64.0;
    double dv = (double)v - 32.0;
    float cw = (float)(512.0 / sqrt(262144.0 + dv * dv + du * du));
    row[u] = (sino - p[e]) * cw;
    __syncthreads();
    float acc = 0.125f * row[u];
#pragma unroll
    for (int d = 1; d <= 63; d += 2) {
        float f = (float)(-0.5 / (M_PI * M_PI * (double)(d * d)));
        float lo = (u - d >= 0) ? row[u - d] : 0.0f;
        float hi = (u + d < NU) ? row[u + d] : 0.0f;
        acc += f * (lo + hi);
    }
    resT[a * RT_PITCH + (u << 6) + v] = acc;   // [a][u][v]
    if (v == 0) {                              // zero the 4 pad u-columns (256 floats)
        resT[a * RT_PITCH + 8192 + u]       = 0.0f;
        resT[a * RT_PITCH + 8192 + 128 + u] = 0.0f;
    }
}

// ---------------- back projection: lanes = v, slab-free, 4x-unrolled u-loop ----------------
// R9 body (2-candidate enumeration from tvlo, register z-splat) + 4 independent
// rv loads per iteration for memory-level parallelism. u's below u_lo / above
// u_hi self-zero via clamped weights; u>127 reads the zeroed pad columns.
#define BP_BODY(RV, UU) do {                                                        \
    const float pu = fmaf(-(UU), sn, c512);                                         \
    const float qu = fmaf((UU), c, s512);                                           \
    const float arg  = fmaf((UU), (UU), s2);                                        \
    const float invn = __builtin_amdgcn_rsqf(arg);                                  \
    const float nn   = arg * invn;                                                  \
    const float i0f  = ceilf(fmaf(tDL, nn, cK));                                    \
    const float ell0 = fmaf(i0f, F_DL, F_L0);                                       \
    v2f tp; tp.x = ell0 * invn; tp.y = fmaf(F_DL, invn, tp.x);                      \
    const v2f pu2 = {pu, pu}, qu2 = {qu, qu};                                       \
    v2f wx = __builtin_elementwise_max(                                             \
        one2 - __builtin_elementwise_abs(__builtin_elementwise_fma(tp, pu2, mVx)), zero2); \
    v2f wy = __builtin_elementwise_max(                                             \
        one2 - __builtin_elementwise_abs(__builtin_elementwise_fma(tp, qu2, mVy)), zero2); \
    v2f val = wx * wy * (v2f){(RV), (RV)};                                          \
    const v2f fz2 = __builtin_elementwise_fma(tp, vv2, (v2f){31.5f, 31.5f});        \
    const v2f g = fz2 - b0;                                                         \
    D0 = __builtin_elementwise_fma(__builtin_elementwise_max(                       \
             one2 - __builtin_elementwise_abs(g), zero2), val, D0);                 \
    D1 = __builtin_elementwise_fma(__builtin_elementwise_max(                       \
             one2 - __builtin_elementwise_abs(g - one2), zero2), val, D1);          \
    D2 = __builtin_elementwise_fma(__builtin_elementwise_max(                       \
             one2 - __builtin_elementwise_abs(g - two2), zero2), val, D2);          \
    D3 = __builtin_elementwise_fma(__builtin_elementwise_max(                       \
             one2 - __builtin_elementwise_abs(g - thr2), zero2), val, D3);          \
} while (0)

__global__ __launch_bounds__(512, 6) void bp_gather8(const float* __restrict__ resT,
                                                     float* __restrict__ out) {
    __shared__ float s_acc[8 * 64];       // per-wave z-accumulator columns

    const int tid  = threadIdx.x;
    const int lane = tid & 63;            // = v
    const int wv   = tid >> 6;            // wave 0..7
    const int y    = blockIdx.x >> 4;     // 0..127
    const int x16  = blockIdx.x & 15;     // 0..15
    const int xi   = x16 * 8 + wv;        // 8 consecutive x per block

    const float x0 = (float)xi - 63.5f;
    const float y0 = (float)y  - 63.5f;
    const float vvf = (float)lane - 31.5f;
    const float s2  = fmaf(vvf, vvf, 262144.0f);   // vv^2 + 512^2
    const v2f vv2   = {vvf, vvf};
    const v2f one2  = {1.0f, 1.0f}, zero2 = {0.0f, 0.0f};
    const v2f two2  = {2.0f, 2.0f}, thr2  = {3.0f, 3.0f};
    const float cK  = -(F_L0 * INV_DL) - 1.0e-3f;

    s_acc[tid] = 0.0f;

    for (int a = 0; a < NA; ++a) {
        const float c  = CSA[a];
        const float sn = SNA[a];
        const float c512 = 512.0f * c;
        const float s512 = 512.0f * sn;
        const float ab1  = fabsf(c) + fabsf(sn);

        const float Vx  = x0 + 256.0f * c;
        const float Vy  = y0 + 256.0f * sn;
        const float rho = fmaf(x0, c, fmaf(y0, sn, 256.0f));   // in [166, 346]
        const float tvlo = (rho - ab1) * (1.0f / 512.0f);
        // u-window (per-wave)
        const float yp = y0 * c - x0 * sn;
        const float rlo = __builtin_amdgcn_rcpf(rho - ab1);
        const float rhi = __builtin_amdgcn_rcpf(rho + ab1);
        const float A = yp - ab1, B = yp + ab1;
        const float uumin = 512.0f * A * ((A >= 0.0f) ? rhi : rlo);
        const float uumax = 512.0f * B * ((B >= 0.0f) ? rlo : rhi);
        const int u_lo = max(0,   (int)ceilf(uumin + 63.49f));
        const int u_hi = min(127, (int)floorf(uumax + 63.51f));
        if (u_lo > u_hi) continue;

        // static z-bin base; candidates have tp in [tvlo, tvlo + 2*DL/nn]
        const float tloM = tvlo - 1.0e-3f;
        const float thiM = tvlo + 7.2e-3f;     // >= tvlo + 2*DL/512 + slack
        const float Zmin = fmaf(vvf, (vvf >= 0.0f) ? tloM : thiM, 31.5f);
        const float izbf = floorf(Zmin);       // in [8, 53] (cone reach, no clamp)
        const int   izb  = (int)izbf;
        const v2f b0 = {izbf, izbf};
        const float tDL = tvlo * INV_DL;

        v2f D0 = zero2, D1 = zero2, D2 = zero2, D3 = zero2;
        const v2f mVx = {-Vx, -Vx}, mVy = {-Vy, -Vy};

        const int u_lo4 = u_lo & ~3;
        const float* ru = resT + a * RT_PITCH + (u_lo4 << 6) + lane;
        float uuf = (float)u_lo4 - 63.5f;
#pragma unroll 1
        for (int u = u_lo4; u <= u_hi; u += 4, uuf += 4.0f, ru += 256) {
            const float rva = ru[0];       // 4 independent loads -> 4-deep MLP
            const float rvb = ru[64];
            const float rvc = ru[128];
            const float rvd = ru[192];
            BP_BODY(rva, uuf);
            BP_BODY(rvb, uuf + 1.0f);
            BP_BODY(rvc, uuf + 2.0f);
            BP_BODY(rvd, uuf + 3.0f);
        }

        float* accw = s_acc + (wv << 6);       // wave-private column
        atomicAdd(&accw[izb],     D0.x + D0.y);
        atomicAdd(&accw[izb + 1], D1.x + D1.y);
        atomicAdd(&accw[izb + 2], D2.x + D2.y);
        atomicAdd(&accw[izb + 3], D3.x + D3.y);
    }
    __syncthreads();

    // writeout: 8 consecutive x per 8 lanes -> 32B chunks
    const int z  = tid >> 3;
    const int w8 = tid & 7;
    out[(z << 14) + (y << 7) + x16 * 8 + w8] = s_acc[(w8 << 6) + z] * F_STEP;
}

extern "C" void kernel_launch(void* const* d_in, const int* in_sizes, int n_in,
                              void* d_out, int out_size, void* d_ws, size_t ws_size,
                              hipStream_t stream) {
    const float* x = (const float*)d_in[0];   // [1,1,64,128,128]
    const float* p = (const float*)d_in[1];   // [1,1,24,64,128]
    float* out  = (float*)d_out;              // [1,1,64,128,128]
    float* resT = (float*)d_ws;               // padded transposed residual, NA*RT_PITCH floats
    float* part = resT + NA * RT_PITCH;       // 2 FP segments, 2*NRAYS floats

    dim3 fpg(NRAYS / 256, 2);
    fp_seg_kernel<<<fpg, 256, 0, stream>>>(x, part);
    ramp_kernel<<<NA * NV, NU, 0, stream>>>(part, p, resT);
    bp_gather8<<<16 * 128, 512, 0, stream>>>(resT, out);
}

// Round 11
// 593.508 us; speedup vs baseline: 1.0907x; 1.0907x over previous
//
#include <hip/hip_runtime.h>
#include <math.h>

// ---- geometry constants (match reference) ----
#define NA   24
#define NU   128
#define NV   64
#define NW   128   // volume W (x)
#define NH   128   // volume H (y)
#define ND   64    // volume D (z)
#define NS   128   // samples per ray
#define F_STEP 1.5625f            // 2*HS/S = 200/128
#define F_DL  (200.0f / 127.0f)   // linspace(156,356,128) spacing
#define F_L0  156.0f
#define INV_DL (127.0f / 200.0f)

#define NRAYS (NA * NV * NU)      // 196608
#define VOX   (NW * NH * ND)      // 1048576

typedef float v2f __attribute__((ext_vector_type(2)));

// cos/sin(k*15 deg)
__device__ __constant__ float CSA[NA] = {
    1.0f,  0.96592582628906829f,  0.86602540378443865f,  0.70710678118654752f,
    0.5f,  0.25881904510252076f,  0.0f,                 -0.25881904510252076f,
   -0.5f, -0.70710678118654752f, -0.86602540378443865f, -0.96592582628906829f,
   -1.0f, -0.96592582628906829f, -0.86602540378443865f, -0.70710678118654752f,
   -0.5f, -0.25881904510252076f,  0.0f,                  0.25881904510252076f,
    0.5f,  0.70710678118654752f,  0.86602540378443865f,  0.96592582628906829f
};
__device__ __constant__ float SNA[NA] = {
    0.0f,  0.25881904510252076f,  0.5f,                  0.70710678118654752f,
    0.86602540378443865f,  0.96592582628906829f,  1.0f,  0.96592582628906829f,
    0.86602540378443865f,  0.70710678118654752f,  0.5f,  0.25881904510252076f,
    0.0f, -0.25881904510252076f, -0.5f,                 -0.70710678118654752f,
   -0.86602540378443865f, -0.96592582628906829f, -1.0f, -0.96592582628906829f,
   -0.86602540378443865f, -0.70710678118654752f, -0.5f, -0.25881904510252076f
};

// Per-ray geometry for FP.
__device__ __forceinline__ void ray_setup(int a, int v, int u,
                                          float& sx, float& sy,
                                          float& dx, float& dy, float& dz) {
    float ang = (float)((double)a * (15.0 * M_PI / 180.0));
    float c = cosf(ang), s = sinf(ang);
    float uu = (float)u - 63.5f;
    float vv = (float)v - 31.5f;
    float ux = 512.0f * c - uu * s;
    float uy = 512.0f * s + uu * c;
    float uz = vv;
    float invn = 1.0f / sqrtf(ux * ux + uy * uy + uz * uz);
    dx = ux * invn; dy = uy * invn; dz = uz * invn;
    sx = -256.0f * c; sy = -256.0f * s;
}

// ---------------- forward projection, segmented over ell ----------------
__global__ __launch_bounds__(256) void fp_seg_kernel(const float* __restrict__ vol,
                                                     float* __restrict__ part) {
    int r = blockIdx.x * blockDim.x + threadIdx.x;
    int seg = blockIdx.y;
    int u = r & (NU - 1);
    int v = (r >> 7) & (NV - 1);
    int a = r >> 13;

    float sx, sy, dx, dy, dz;
    ray_setup(a, v, u, sx, sy, dx, dy, dz);

    float rx = 1.0f / dx, ry = 1.0f / dy, rz = 1.0f / dz;
    float ex0 = (-64.55f - sx) * rx, ex1 = (64.55f - sx) * rx;
    float ey0 = (-64.55f - sy) * ry, ey1 = (64.55f - sy) * ry;
    float ez0 = (-32.55f) * rz,      ez1 = (32.55f) * rz;
    float llo = fmaxf(fmaxf(fminf(ex0, ex1), fminf(ey0, ey1)), fminf(ez0, ez1));
    float lhi = fminf(fminf(fmaxf(ex0, ex1), fmaxf(ey0, ey1)), fmaxf(ez0, ez1));
    int i_lo = max(seg * 64,      (int)ceilf((llo - F_L0) * INV_DL));
    int i_hi = min(seg * 64 + 63, (int)floorf((lhi - F_L0) * INV_DL));

    float acc = 0.0f;
    for (int i = i_lo; i <= i_hi; ++i) {
        float ell = F_L0 + F_DL * (float)i;
        float cx = sx + ell * dx + 63.5f;
        float cy = sy + ell * dy + 63.5f;
        float cz =      ell * dz + 31.5f;
        float fx = floorf(cx), fy = floorf(cy), fz = floorf(cz);
        int ix = (int)fx, iy = (int)fy, iz = (int)fz;
        float wx1 = cx - fx, wy1 = cy - fy, wz1 = cz - fz;
        float wx0 = 1.0f - wx1, wy0 = 1.0f - wy1, wz0 = 1.0f - wz1;
        bool bx0 = (unsigned)ix < NW,      bx1 = (unsigned)(ix + 1) < NW;
        bool by0 = (unsigned)iy < NH,      by1 = (unsigned)(iy + 1) < NH;
        bool bz0 = (unsigned)iz < ND,      bz1 = (unsigned)(iz + 1) < ND;
        long base = ((long)iz * NH + iy) * NW + ix;
        float v000 = (bz0 && by0 && bx0) ? vol[base]                 : 0.0f;
        float v001 = (bz0 && by0 && bx1) ? vol[base + 1]             : 0.0f;
        float v010 = (bz0 && by1 && bx0) ? vol[base + NW]            : 0.0f;
        float v011 = (bz0 && by1 && bx1) ? vol[base + NW + 1]        : 0.0f;
        float v100 = (bz1 && by0 && bx0) ? vol[base + NH * NW]       : 0.0f;
        float v101 = (bz1 && by0 && bx1) ? vol[base + NH * NW + 1]   : 0.0f;
        float v110 = (bz1 && by1 && bx0) ? vol[base + NH * NW + NW]  : 0.0f;
        float v111 = (bz1 && by1 && bx1) ? vol[base + NH * NW + NW + 1] : 0.0f;
        acc += wz0 * (wy0 * (wx0 * v000 + wx1 * v001) +
                      wy1 * (wx0 * v010 + wx1 * v011)) +
               wz1 * (wy0 * (wx0 * v100 + wx1 * v101) +
                      wy1 * (wx0 * v110 + wx1 * v111));
    }
    part[seg * NRAYS + r] = acc;
}

// ------- residual + cw + Ram-Lak; writes TRANSPOSED resT[a][u][v] -------
__global__ __launch_bounds__(NU) void ramp_kernel(const float* __restrict__ part,
                                                  const float* __restrict__ p,
                                                  float* __restrict__ resT) {
    __shared__ float row[NU];
    int rowid = blockIdx.x;          // a*NV + v
    int u = threadIdx.x;
    int e = rowid * NU + u;
    int a = rowid >> 6;
    int v = rowid & (NV - 1);
    float sino = (part[e] + part[NRAYS + e]) * F_STEP;
    double du = (double)u - 64.0;
    double dv = (double)v - 32.0;
    float cw = (float)(512.0 / sqrt(262144.0 + dv * dv + du * du));
    row[u] = (sino - p[e]) * cw;
    __syncthreads();
    float acc = 0.125f * row[u];
#pragma unroll
    for (int d = 1; d <= 63; d += 2) {
        float f = (float)(-0.5 / (M_PI * M_PI * (double)(d * d)));
        float lo = (u - d >= 0) ? row[u - d] : 0.0f;
        float hi = (u + d < NU) ? row[u + d] : 0.0f;
        acc += f * (lo + hi);
    }
    resT[(a << 13) + (u << 6) + v] = acc;   // [a][u][v]
}

// ---------------- back projection: dual-angle interleaved gather ----------------
// Wave = one xy-column, lane = v. Angles (j, j+12) processed in ONE fused loop:
// 2 independent dependency chains + 2 loads in flight cover the per-angle serial
// prologue (trig->rho->rcp->window->addr->load) that pinned R8/R9/R10 at ~475us.
// Iterations outside an angle's true support self-zero via clamped weights;
// u_start = max(0, min(u_lo, 128-trips)) keeps every access in [0,127].

#define SETUP_ANGLE(S, CC, SS)                                                   \
    const float c##S = (CC), sn##S = (SS);                                       \
    const float c512##S = 512.0f * c##S;                                         \
    const float s512##S = 512.0f * sn##S;                                        \
    const float rho##S = fmaf(x0, c##S, fmaf(y0, sn##S, 256.0f));                \
    const float Vx##S = x0 + 256.0f * c##S;                                      \
    const float Vy##S = y0 + 256.0f * sn##S;                                     \
    const float tvlo##S = (rho##S - ab1) * (1.0f / 512.0f);                      \
    const float yp##S = y0 * c##S - x0 * sn##S;                                  \
    const float rl##S = __builtin_amdgcn_rcpf(rho##S - ab1);                     \
    const float rh##S = __builtin_amdgcn_rcpf(rho##S + ab1);                     \
    const float A##S = yp##S - ab1, B##S = yp##S + ab1;                          \
    const float um##S = 512.0f * A##S * ((A##S >= 0.0f) ? rh##S : rl##S);        \
    const float uM##S = 512.0f * B##S * ((B##S >= 0.0f) ? rl##S : rh##S);        \
    const int u_lo##S = max(0,   (int)ceilf(um##S + 63.49f));                    \
    const int u_hi##S = min(127, (int)floorf(uM##S + 63.51f));                   \
    const int len##S = max(0, u_hi##S - u_lo##S + 1);                            \
    const float Zmin##S = fmaf(vvf, (vvf >= 0.0f) ? (tvlo##S - 1.0e-3f)          \
                                                  : (tvlo##S + 7.2e-3f), 31.5f); \
    const float izbf##S = floorf(Zmin##S);                                       \
    const int   izb##S  = (int)izbf##S;                                          \
    const v2f b0##S = {izbf##S, izbf##S};                                        \
    const float tDL##S = tvlo##S * INV_DL;                                       \
    const v2f mVx##S = {-Vx##S, -Vx##S}, mVy##S = {-Vy##S, -Vy##S};

#define BP_BODY2(S, RV, UU) do {                                                 \
    const float pu = fmaf(-(UU), sn##S, c512##S);                                \
    const float qu = fmaf((UU), c##S, s512##S);                                  \
    const float arg  = fmaf((UU), (UU), s2);                                     \
    const float invn = __builtin_amdgcn_rsqf(arg);                               \
    const float nn   = arg * invn;                                               \
    const float i0f  = ceilf(fmaf(tDL##S, nn, cK));                              \
    const float ell0 = fmaf(i0f, F_DL, F_L0);                                    \
    v2f tp; tp.x = ell0 * invn; tp.y = fmaf(F_DL, invn, tp.x);                   \
    const v2f pu2 = {pu, pu}, qu2 = {qu, qu};                                    \
    v2f wx = __builtin_elementwise_max(                                          \
        one2 - __builtin_elementwise_abs(__builtin_elementwise_fma(tp, pu2, mVx##S)), zero2); \
    v2f wy = __builtin_elementwise_max(                                          \
        one2 - __builtin_elementwise_abs(__builtin_elementwise_fma(tp, qu2, mVy##S)), zero2); \
    v2f val = wx * wy * (v2f){(RV), (RV)};                                       \
    const v2f fz2 = __builtin_elementwise_fma(tp, vv2, h31);                     \
    const v2f g = fz2 - b0##S;                                                   \
    AC0##S = __builtin_elementwise_fma(__builtin_elementwise_max(                \
             one2 - __builtin_elementwise_abs(g), zero2), val, AC0##S);          \
    AC1##S = __builtin_elementwise_fma(__builtin_elementwise_max(                \
             one2 - __builtin_elementwise_abs(g - one2), zero2), val, AC1##S);   \
    AC2##S = __builtin_elementwise_fma(__builtin_elementwise_max(                \
             one2 - __builtin_elementwise_abs(g - two2), zero2), val, AC2##S);   \
    AC3##S = __builtin_elementwise_fma(__builtin_elementwise_max(                \
             one2 - __builtin_elementwise_abs(g - thr2), zero2), val, AC3##S);   \
} while (0)

__global__ __launch_bounds__(256, 6) void bp_gather9(const float* __restrict__ resT,
                                                     float* __restrict__ out) {
    __shared__ float s_acc[4 * 64];       // per-wave z-accumulator columns

    const int tid  = threadIdx.x;
    const int lane = tid & 63;            // = v
    const int wv   = tid >> 6;            // wave 0..3
    const int y    = blockIdx.x & 127;    // y-major: adjacent blocks differ in y
    const int xq   = blockIdx.x >> 7;     // 0..31
    const int xi   = xq * 4 + wv;         // 4 consecutive x per block

    const float x0 = (float)xi - 63.5f;
    const float y0 = (float)y  - 63.5f;
    const float vvf = (float)lane - 31.5f;
    const float s2  = fmaf(vvf, vvf, 262144.0f);   // vv^2 + 512^2
    const v2f vv2   = {vvf, vvf};
    const v2f one2  = {1.0f, 1.0f}, zero2 = {0.0f, 0.0f};
    const v2f two2  = {2.0f, 2.0f}, thr2  = {3.0f, 3.0f};
    const v2f h31   = {31.5f, 31.5f};
    const float cK  = -(F_L0 * INV_DL) - 1.0e-3f;

    s_acc[tid] = 0.0f;

    for (int j = 0; j < NA / 2; ++j) {
        const float cj  = CSA[j];
        const float snj = SNA[j];
        const float ab1 = fabsf(cj) + fabsf(snj);

        SETUP_ANGLE(0, cj, snj);            // angle j
        SETUP_ANGLE(1, -cj, -snj);          // angle j+12 (opposite)

        const int trips = max(len0, len1);
        if (trips == 0) continue;
        const int us0 = max(0, min(u_lo0, 128 - trips));
        const int us1 = max(0, min(u_lo1, 128 - trips));

        v2f AC00 = zero2, AC10 = zero2, AC20 = zero2, AC30 = zero2;
        v2f AC01 = zero2, AC11 = zero2, AC21 = zero2, AC31 = zero2;

        const float* ru0 = resT + (j << 13)        + (us0 << 6) + lane;
        const float* ru1 = resT + ((j + 12) << 13) + (us1 << 6) + lane;
        float uu0 = (float)us0 - 63.5f;
        float uu1 = (float)us1 - 63.5f;
#pragma unroll 1
        for (int k = 0; k < trips; ++k, uu0 += 1.0f, uu1 += 1.0f, ru0 += 64, ru1 += 64) {
            const float rv0 = ru0[0];         // 2 independent loads in flight
            const float rv1 = ru1[0];
            BP_BODY2(0, rv0, uu0);
            BP_BODY2(1, rv1, uu1);
        }

        float* accw = s_acc + (wv << 6);      // wave-private column
        atomicAdd(&accw[izb0],     AC00.x + AC00.y);
        atomicAdd(&accw[izb0 + 1], AC10.x + AC10.y);
        atomicAdd(&accw[izb0 + 2], AC20.x + AC20.y);
        atomicAdd(&accw[izb0 + 3], AC30.x + AC30.y);
        atomicAdd(&accw[izb1],     AC01.x + AC01.y);
        atomicAdd(&accw[izb1 + 1], AC11.x + AC11.y);
        atomicAdd(&accw[izb1 + 2], AC21.x + AC21.y);
        atomicAdd(&accw[izb1 + 3], AC31.x + AC31.y);
    }
    __syncthreads();

    // writeout: 4 consecutive x per 4 lanes -> 16B chunks
    const int z  = tid >> 2;
    const int w4 = tid & 3;
    out[(z << 14) + (y << 7) + xq * 4 + w4] = s_acc[(w4 << 6) + z] * F_STEP;
}

extern "C" void kernel_launch(void* const* d_in, const int* in_sizes, int n_in,
                              void* d_out, int out_size, void* d_ws, size_t ws_size,
                              hipStream_t stream) {
    const float* x = (const float*)d_in[0];   // [1,1,64,128,128]
    const float* p = (const float*)d_in[1];   // [1,1,24,64,128]
    float* out  = (float*)d_out;              // [1,1,64,128,128]
    float* resT = (float*)d_ws;               // transposed filtered residual, NRAYS floats
    float* part = resT + NRAYS;               // 2 FP segments, 2*NRAYS floats

    dim3 fpg(NRAYS / 256, 2);
    fp_seg_kernel<<<fpg, 256, 0, stream>>>(x, part);
    ramp_kernel<<<NA * NV, NU, 0, stream>>>(part, p, resT);
    bp_gather9<<<128 * 32, 256, 0, stream>>>(resT, out);
}